// Round 6
// baseline (195.974 us; speedup 1.0000x reference)
//
#include <hip/hip_runtime.h>

#define NCH 30
#define F2PC 15              // float2 per cell (120 B)
#define TILE 64              // cells per wave-tile
#define TPB 64               // one wave per block: no barrier convoys
#define MAXB 2560            // 10 blocks/CU (LDS-capped: 10 * 15360 B < 160 KiB) * 256 CUs

typedef float fvec2 __attribute__((ext_vector_type(2)));
typedef float fvec4 __attribute__((ext_vector_type(4)));

__device__ __forceinline__ float iou_fn(float x1, float y1, float w1, float h1,
                                        float x2, float y2, float w2, float h2) {
    float a1 = w1 * h1, a2 = w2 * h2;
    float left  = fmaxf(x1 - w1 * 0.5f, x2 - w2 * 0.5f);
    float right = fminf(x1 + w1 * 0.5f, x2 + w2 * 0.5f);
    float top   = fmaxf(y1 - h1 * 0.5f, y2 - h2 * 0.5f);
    float bot   = fminf(y1 + h1 * 0.5f, y2 + h2 * 0.5f);
    float iw = fmaxf(right - left, 0.0f);
    float ih = fmaxf(bot - top, 0.0f);
    float inter = iw * ih;
    float uni = a1 + a2 - inter;
    return (inter > 0.0f) ? (inter / uni) : 0.0f;
}

__device__ __forceinline__ void cell_losses(const float* p, const float* t,
                                            float& coord, float& lobj,
                                            float& lnoobj, float& lclass) {
    float obj_f = (t[0] == 1.0f) ? 1.0f : 0.0f;

    float iou1 = iou_fn(p[1], p[2], p[3], p[4], t[1], t[2], t[3], t[4]);
    float iou2 = iou_fn(t[6], t[7], t[8], t[9], t[1], t[2], t[3], t[4]);
    bool r = iou1 > iou2;

    float px = r ? p[1] : p[6], py = r ? p[2] : p[7];
    float pw = r ? p[3] : p[8], ph = r ? p[4] : p[9];
    float tx = r ? t[1] : t[6], ty = r ? t[2] : t[7];
    float tw = r ? t[3] : t[8], th = r ? t[4] : t[9];

    float dx = px - tx, dy = py - ty;
    float cxy = dx * dx + dy * dy;
    float swv = sqrtf(pw) - sqrtf(tw), shv = sqrtf(ph) - sqrtf(th);
    float cwh = swv * swv + shv * shv;

    float conf_resp  = r ? p[0] : p[5];
    float iou_resp   = r ? iou1 : iou2;
    float conf_other = r ? p[5] : p[0];
    float dconf = conf_resp - iou_resp;

    coord  += obj_f * (cxy + cwh);
    lobj   += obj_f * dconf * dconf;
    lnoobj += obj_f * conf_other * conf_other
            + (1.0f - obj_f) * (p[0] * p[0] + p[5] * p[5]);

    float cls = 0.0f;
#pragma unroll
    for (int i = 10; i < NCH; i++) { float e = p[i] - t[i]; cls += e * e; }
    lclass += obj_f * cls;
}

// Depth-2 NT pipeline: two named register buffers (A/B, static names per
// rule #20), manually unrolled 2-phase loop. Per phase: ds_write buffer X
// (counted vmcnt: only X's loads are waited, the other buffer's 16 stay in
// flight), immediately reuse X's regs to issue tile t+2's NT loads, barrier
// (1-wave: no vmcnt drain -- plain reg loads need no drain at a barrier),
// compute. In-flight per wave never drops below ~16 KB.
#define LOADT(RP, RT, RP7, RT7, tile_) do {                                              \
    const long long b4_ = (long long)(tile_) * 480;                                      \
    _Pragma("unroll")                                                                    \
    for (int k_ = 0; k_ < 7; k_++) {                                                     \
        RP[k_] = __builtin_nontemporal_load(reinterpret_cast<const fvec4*>(pred) + b4_ + k_ * 64 + lane); \
        RT[k_] = __builtin_nontemporal_load(reinterpret_cast<const fvec4*>(targ) + b4_ + k_ * 64 + lane); \
    }                                                                                    \
    RP7 = __builtin_nontemporal_load(reinterpret_cast<const fvec2*>(pred) + 2 * b4_ + 896 + lane); \
    RT7 = __builtin_nontemporal_load(reinterpret_cast<const fvec2*>(targ) + 2 * b4_ + 896 + lane); \
} while (0)

#define STORE_LDS(RP, RT, RP7, RT7) do {                                                 \
    _Pragma("unroll")                                                                    \
    for (int k_ = 0; k_ < 7; k_++) {                                                     \
        sp4[k_ * 64 + lane] = RP[k_];                                                    \
        st4[k_ * 64 + lane] = RT[k_];                                                    \
    }                                                                                    \
    reinterpret_cast<fvec2*>(sp4)[896 + lane] = RP7;                                     \
    reinterpret_cast<fvec2*>(st4)[896 + lane] = RT7;                                     \
} while (0)

#define COMPUTE() do {                                                                   \
    float p_[NCH], t_[NCH];                                                              \
    const fvec2* pp_ = reinterpret_cast<const fvec2*>(sp4) + lane * F2PC;                \
    const fvec2* tp_ = reinterpret_cast<const fvec2*>(st4) + lane * F2PC;                \
    _Pragma("unroll")                                                                    \
    for (int k_ = 0; k_ < F2PC; k_++) { fvec2 v_ = pp_[k_]; p_[2 * k_] = v_.x; p_[2 * k_ + 1] = v_.y; } \
    _Pragma("unroll")                                                                    \
    for (int k_ = 0; k_ < F2PC; k_++) { fvec2 v_ = tp_[k_]; t_[2 * k_] = v_.x; t_[2 * k_ + 1] = v_.y; } \
    cell_losses(p_, t_, coord, lobj, lnoobj, lclass);                                    \
} while (0)

__global__ __launch_bounds__(TPB) void yolo_main(
        const float* __restrict__ pred, const float* __restrict__ targ,
        float4* __restrict__ partials, int n_full, int n_cells) {
    __shared__ fvec4 sp4[TILE * F2PC / 2];   // 7680 B (480 fvec4)
    __shared__ fvec4 st4[TILE * F2PC / 2];   // 7680 B

    const int lane = threadIdx.x;
    float coord = 0.f, lobj = 0.f, lnoobj = 0.f, lclass = 0.f;

    fvec4 rpA[7], rtA[7]; fvec2 rpA7, rtA7;
    fvec4 rpB[7], rtB[7]; fvec2 rpB7, rtB7;

    const int stride = gridDim.x;
    int tc = blockIdx.x;                  // next tile to compute (data in A first)

    if (tc < n_full)              LOADT(rpA, rtA, rpA7, rtA7, tc);
    if (tc + stride < n_full)     LOADT(rpB, rtB, rpB7, rtB7, tc + stride);

    for (;;) {
        // ---- phase A: compute tile tc from buffer A ----
        if (tc >= n_full) break;
        __syncthreads();                          // LDS free (prev compute done)
        STORE_LDS(rpA, rtA, rpA7, rtA7);          // waits A's loads only (counted vmcnt)
        if (tc + 2 * stride < n_full)             // refill A with tile t+2; B stays in flight
            LOADT(rpA, rtA, rpA7, rtA7, tc + 2 * stride);
        __syncthreads();
        COMPUTE();
        tc += stride;

        // ---- phase B: compute tile tc from buffer B ----
        if (tc >= n_full) break;
        __syncthreads();
        STORE_LDS(rpB, rtB, rpB7, rtB7);
        if (tc + 2 * stride < n_full)
            LOADT(rpB, rtB, rpB7, rtB7, tc + 2 * stride);
        __syncthreads();
        COMPUTE();
        tc += stride;
    }

    // tail cells (n_cells % TILE — zero for the bench shape), block 0, direct loads
    if (blockIdx.x == 0) {
        int cell = n_full * TILE + lane;
        if (cell < n_cells) {
            float p[NCH], tt[NCH];
            const fvec2* pp = reinterpret_cast<const fvec2*>(pred) + (long long)cell * F2PC;
            const fvec2* tp = reinterpret_cast<const fvec2*>(targ) + (long long)cell * F2PC;
#pragma unroll
            for (int k = 0; k < F2PC; k++) { fvec2 v = pp[k]; p[2 * k] = v.x; p[2 * k + 1] = v.y; }
#pragma unroll
            for (int k = 0; k < F2PC; k++) { fvec2 v = tp[k]; tt[2 * k] = v.x; tt[2 * k + 1] = v.y; }
            cell_losses(p, tt, coord, lobj, lnoobj, lclass);
        }
    }

    // single-wave shuffle reduction
#pragma unroll
    for (int off = 32; off > 0; off >>= 1) {
        coord  += __shfl_down(coord, off);
        lobj   += __shfl_down(lobj, off);
        lnoobj += __shfl_down(lnoobj, off);
        lclass += __shfl_down(lclass, off);
    }
    if (lane == 0) partials[blockIdx.x] = make_float4(coord, lobj, lnoobj, lclass);
}

__global__ __launch_bounds__(256) void yolo_reduce(
        const float4* __restrict__ partials, int nparts,
        float* __restrict__ out, double inv_bs) {
    double s0 = 0.0, s1 = 0.0, s2 = 0.0, s3 = 0.0;
    for (int i = threadIdx.x; i < nparts; i += 256) {
        float4 v = partials[i];
        s0 += (double)v.x; s1 += (double)v.y;
        s2 += (double)v.z; s3 += (double)v.w;
    }
#pragma unroll
    for (int off = 32; off > 0; off >>= 1) {
        s0 += __shfl_down(s0, off);
        s1 += __shfl_down(s1, off);
        s2 += __shfl_down(s2, off);
        s3 += __shfl_down(s3, off);
    }
    __shared__ double red[4][4];
    int lane = threadIdx.x & 63;
    int wid  = threadIdx.x >> 6;
    if (lane == 0) {
        red[wid][0] = s0; red[wid][1] = s1;
        red[wid][2] = s2; red[wid][3] = s3;
    }
    __syncthreads();
    if (threadIdx.x == 0) {
        double a0 = 0, a1 = 0, a2 = 0, a3 = 0;
        for (int w = 0; w < 4; w++) {
            a0 += red[w][0]; a1 += red[w][1];
            a2 += red[w][2]; a3 += red[w][3];
        }
        double cd = a0 * 5.0 * inv_bs;   // LAMBDA_COORD
        double o  = a1 * inv_bs;
        double n  = a2 * 0.5 * inv_bs;   // LAMBDA_NOOBJ
        double cl = a3 * inv_bs;
        out[0] = (float)cd;
        out[1] = (float)o;
        out[2] = (float)n;
        out[3] = (float)cl;
        out[4] = (float)(cd + o + n + cl);
    }
}

extern "C" void kernel_launch(void* const* d_in, const int* in_sizes, int n_in,
                              void* d_out, int out_size, void* d_ws, size_t ws_size,
                              hipStream_t stream) {
    const float* pred = (const float*)d_in[0];
    const float* targ = (const float*)d_in[1];
    float* out = (float*)d_out;
    float4* partials = (float4*)d_ws;

    int n_cells = in_sizes[0] / NCH;          // batch * 7 * 7
    int batch   = n_cells / 49;
    int n_full  = n_cells / TILE;

    int grid = (n_full < 1) ? 1 : (n_full < MAXB ? n_full : MAXB);

    // workspace guard: one float4 per block
    int max_parts = (int)(ws_size / sizeof(float4));
    if (max_parts >= 1 && grid > max_parts) grid = max_parts;

    yolo_main<<<grid, TPB, 0, stream>>>(pred, targ, partials, n_full, n_cells);
    yolo_reduce<<<1, 256, 0, stream>>>(partials, grid, out, 1.0 / (double)batch);
}

// Round 7
// 191.752 us; speedup vs baseline: 1.0220x; 1.0220x over previous
//
#include <hip/hip_runtime.h>

#define NCH 30
#define F2PC 15              // float2 per cell (120 B)
#define TILE 64              // cells per tile (= 480 fvec4 per tensor = 7680 B)
#define TPB 64               // one wave per block
#define MAXB 1280            // 5 blocks/CU (LDS 30,720 B/block; 160KiB/30.7KB = 5) * 256 CUs

typedef float fvec2 __attribute__((ext_vector_type(2)));
typedef float fvec4 __attribute__((ext_vector_type(4)));

__device__ __forceinline__ float iou_fn(float x1, float y1, float w1, float h1,
                                        float x2, float y2, float w2, float h2) {
    float a1 = w1 * h1, a2 = w2 * h2;
    float left  = fmaxf(x1 - w1 * 0.5f, x2 - w2 * 0.5f);
    float right = fminf(x1 + w1 * 0.5f, x2 + w2 * 0.5f);
    float top   = fmaxf(y1 - h1 * 0.5f, y2 - h2 * 0.5f);
    float bot   = fminf(y1 + h1 * 0.5f, y2 + h2 * 0.5f);
    float iw = fmaxf(right - left, 0.0f);
    float ih = fmaxf(bot - top, 0.0f);
    float inter = iw * ih;
    float uni = a1 + a2 - inter;
    return (inter > 0.0f) ? (inter / uni) : 0.0f;
}

__device__ __forceinline__ void cell_losses(const float* p, const float* t,
                                            float& coord, float& lobj,
                                            float& lnoobj, float& lclass) {
    float obj_f = (t[0] == 1.0f) ? 1.0f : 0.0f;

    float iou1 = iou_fn(p[1], p[2], p[3], p[4], t[1], t[2], t[3], t[4]);
    float iou2 = iou_fn(t[6], t[7], t[8], t[9], t[1], t[2], t[3], t[4]);
    bool r = iou1 > iou2;

    float px = r ? p[1] : p[6], py = r ? p[2] : p[7];
    float pw = r ? p[3] : p[8], ph = r ? p[4] : p[9];
    float tx = r ? t[1] : t[6], ty = r ? t[2] : t[7];
    float tw = r ? t[3] : t[8], th = r ? t[4] : t[9];

    float dx = px - tx, dy = py - ty;
    float cxy = dx * dx + dy * dy;
    float swv = sqrtf(pw) - sqrtf(tw), shv = sqrtf(ph) - sqrtf(th);
    float cwh = swv * swv + shv * shv;

    float conf_resp  = r ? p[0] : p[5];
    float iou_resp   = r ? iou1 : iou2;
    float conf_other = r ? p[5] : p[0];
    float dconf = conf_resp - iou_resp;

    coord  += obj_f * (cxy + cwh);
    lobj   += obj_f * dconf * dconf;
    lnoobj += obj_f * conf_other * conf_other
            + (1.0f - obj_f) * (p[0] * p[0] + p[5] * p[5]);

    float cls = 0.0f;
#pragma unroll
    for (int i = 10; i < NCH; i++) { float e = p[i] - t[i]; cls += e * e; }
    lclass += obj_f * cls;
}

// ---- DMA staging: global_load_lds (16B/lane, NT cpol=2), fire-and-forget ----
// LDS dest is wave-uniform base + lane*16 (m104/m108); global src is per-lane.
// aux=2 sets the NT cache-policy bit (the session's one proven lever).
#define GLDS16(gp, lp)                                                                   \
    __builtin_amdgcn_global_load_lds(                                                    \
        (const __attribute__((address_space(1))) void*)(gp),                             \
        (__attribute__((address_space(3))) void*)(lp), 16, 0, 2)

// one tile = 480 fvec4/tensor = 7*64 + 32: 7 full-wave DMAs + 1 half-wave DMA
// per tensor -> 16 vmcnt increments per ISSUE_TILE (exec-masked instr still
// counts once for the wave).
#define ISSUE_TILE(buf, tile_) do {                                                      \
    const long long b4_ = (long long)(tile_) * 480;                                      \
    const fvec4* gp_ = reinterpret_cast<const fvec4*>(pred) + b4_;                       \
    const fvec4* gt_ = reinterpret_cast<const fvec4*>(targ) + b4_;                       \
    _Pragma("unroll")                                                                    \
    for (int k_ = 0; k_ < 7; k_++) {                                                     \
        GLDS16(gp_ + k_ * 64 + lane, &sbuf[buf][0][k_ * 64]);                            \
        GLDS16(gt_ + k_ * 64 + lane, &sbuf[buf][1][k_ * 64]);                            \
    }                                                                                    \
    if (lane < 32) {                                                                     \
        GLDS16(gp_ + 448 + lane, &sbuf[buf][0][448]);                                    \
        GLDS16(gt_ + 448 + lane, &sbuf[buf][1][448]);                                    \
    }                                                                                    \
} while (0)

// counted waits: in steady state NEVER drain to 0 — the other buffer's 16
// DMAs stay in flight across compute. sched_barrier(0) after each inline-asm
// wait per rule #18 (prevent hoisting of dependent ops above the wait).
#define WAITV16 do { asm volatile("s_waitcnt vmcnt(16)" ::: "memory"); \
                     __builtin_amdgcn_sched_barrier(0); } while (0)
#define WAITV0  do { asm volatile("s_waitcnt vmcnt(0)"  ::: "memory"); \
                     __builtin_amdgcn_sched_barrier(0); } while (0)
// before re-issuing a buffer: make sure this wave's ds_reads of it retired
#define LDS_REUSE_GUARD do { asm volatile("s_waitcnt lgkmcnt(0)" ::: "memory"); \
                             __builtin_amdgcn_sched_barrier(0); } while (0)

#define COMPUTE(buf) do {                                                                \
    float p_[NCH], t_[NCH];                                                              \
    const fvec2* pp_ = reinterpret_cast<const fvec2*>(&sbuf[buf][0][0]) + lane * F2PC;   \
    const fvec2* tp_ = reinterpret_cast<const fvec2*>(&sbuf[buf][1][0]) + lane * F2PC;   \
    _Pragma("unroll")                                                                    \
    for (int k_ = 0; k_ < F2PC; k_++) { fvec2 v_ = pp_[k_]; p_[2 * k_] = v_.x; p_[2 * k_ + 1] = v_.y; } \
    _Pragma("unroll")                                                                    \
    for (int k_ = 0; k_ < F2PC; k_++) { fvec2 v_ = tp_[k_]; t_[2 * k_] = v_.x; t_[2 * k_ + 1] = v_.y; } \
    cell_losses(p_, t_, coord, lobj, lnoobj, lclass);                                    \
} while (0)

__global__ __launch_bounds__(TPB) void yolo_main(
        const float* __restrict__ pred, const float* __restrict__ targ,
        float4* __restrict__ partials, int n_full, int n_cells) {
    __shared__ fvec4 sbuf[2][2][480];   // [buffer][pred/targ][480 fvec4] = 30,720 B

    const int lane = threadIdx.x;
    float coord = 0.f, lobj = 0.f, lnoobj = 0.f, lclass = 0.f;

    const int stride = gridDim.x;
    int tc = blockIdx.x;

    // prologue: prime both buffers (A older than B -> vmcnt(16) retires A)
    if (tc < n_full)          ISSUE_TILE(0, tc);
    if (tc + stride < n_full) ISSUE_TILE(1, tc + stride);

    for (;;) {
        // ---- phase A: buffer 0 holds tile tc ----
        if (tc >= n_full) break;
        if (tc + stride < n_full) { WAITV16; } else { WAITV0; }   // A's DMAs done
        COMPUTE(0);
        LDS_REUSE_GUARD;
        if (tc + 2 * stride < n_full) ISSUE_TILE(0, tc + 2 * stride);
        tc += stride;

        // ---- phase B: buffer 1 holds tile tc ----
        if (tc >= n_full) break;
        if (tc + stride < n_full) { WAITV16; } else { WAITV0; }   // B's DMAs done
        COMPUTE(1);
        LDS_REUSE_GUARD;
        if (tc + 2 * stride < n_full) ISSUE_TILE(1, tc + 2 * stride);
        tc += stride;
    }

    // tail cells (n_cells % TILE — zero for the bench shape), block 0, direct loads
    if (blockIdx.x == 0) {
        int cell = n_full * TILE + lane;
        if (cell < n_cells) {
            float p[NCH], tt[NCH];
            const fvec2* pp = reinterpret_cast<const fvec2*>(pred) + (long long)cell * F2PC;
            const fvec2* tp = reinterpret_cast<const fvec2*>(targ) + (long long)cell * F2PC;
#pragma unroll
            for (int k = 0; k < F2PC; k++) { fvec2 v = pp[k]; p[2 * k] = v.x; p[2 * k + 1] = v.y; }
#pragma unroll
            for (int k = 0; k < F2PC; k++) { fvec2 v = tp[k]; tt[2 * k] = v.x; tt[2 * k + 1] = v.y; }
            cell_losses(p, tt, coord, lobj, lnoobj, lclass);
        }
    }

    // single-wave shuffle reduction
#pragma unroll
    for (int off = 32; off > 0; off >>= 1) {
        coord  += __shfl_down(coord, off);
        lobj   += __shfl_down(lobj, off);
        lnoobj += __shfl_down(lnoobj, off);
        lclass += __shfl_down(lclass, off);
    }
    if (lane == 0) partials[blockIdx.x] = make_float4(coord, lobj, lnoobj, lclass);
}

__global__ __launch_bounds__(256) void yolo_reduce(
        const float4* __restrict__ partials, int nparts,
        float* __restrict__ out, double inv_bs) {
    double s0 = 0.0, s1 = 0.0, s2 = 0.0, s3 = 0.0;
    for (int i = threadIdx.x; i < nparts; i += 256) {
        float4 v = partials[i];
        s0 += (double)v.x; s1 += (double)v.y;
        s2 += (double)v.z; s3 += (double)v.w;
    }
#pragma unroll
    for (int off = 32; off > 0; off >>= 1) {
        s0 += __shfl_down(s0, off);
        s1 += __shfl_down(s1, off);
        s2 += __shfl_down(s2, off);
        s3 += __shfl_down(s3, off);
    }
    __shared__ double red[4][4];
    int lane = threadIdx.x & 63;
    int wid  = threadIdx.x >> 6;
    if (lane == 0) {
        red[wid][0] = s0; red[wid][1] = s1;
        red[wid][2] = s2; red[wid][3] = s3;
    }
    __syncthreads();
    if (threadIdx.x == 0) {
        double a0 = 0, a1 = 0, a2 = 0, a3 = 0;
        for (int w = 0; w < 4; w++) {
            a0 += red[w][0]; a1 += red[w][1];
            a2 += red[w][2]; a3 += red[w][3];
        }
        double cd = a0 * 5.0 * inv_bs;   // LAMBDA_COORD
        double o  = a1 * inv_bs;
        double n  = a2 * 0.5 * inv_bs;   // LAMBDA_NOOBJ
        double cl = a3 * inv_bs;
        out[0] = (float)cd;
        out[1] = (float)o;
        out[2] = (float)n;
        out[3] = (float)cl;
        out[4] = (float)(cd + o + n + cl);
    }
}

extern "C" void kernel_launch(void* const* d_in, const int* in_sizes, int n_in,
                              void* d_out, int out_size, void* d_ws, size_t ws_size,
                              hipStream_t stream) {
    const float* pred = (const float*)d_in[0];
    const float* targ = (const float*)d_in[1];
    float* out = (float*)d_out;
    float4* partials = (float4*)d_ws;

    int n_cells = in_sizes[0] / NCH;          // batch * 7 * 7
    int batch   = n_cells / 49;
    int n_full  = n_cells / TILE;

    int grid = (n_full < 1) ? 1 : (n_full < MAXB ? n_full : MAXB);

    // workspace guard: one float4 per block
    int max_parts = (int)(ws_size / sizeof(float4));
    if (max_parts >= 1 && grid > max_parts) grid = max_parts;

    yolo_main<<<grid, TPB, 0, stream>>>(pred, targ, partials, n_full, n_cells);
    yolo_reduce<<<1, 256, 0, stream>>>(partials, grid, out, 1.0 / (double)batch);
}